// Round 2
// baseline (51237.341 us; speedup 1.0000x reference)
//
#include <hip/hip_runtime.h>
#include <math.h>

#define TT 2048
#define EE 512
#define HDD 512
#define TAGS 32
#define STARTT 30
#define STOPP 31
#define NEGV -10000.0f
#define VCH 256
#define SENT 0xFFFFFFFFu   // hs sentinel: -NaN bit pattern, unreachable for finite h

__device__ __forceinline__ float fsig(float x) {
    return __builtin_amdgcn_rcpf(1.f + __expf(-x));
}
__device__ __forceinline__ float ftanh(float x) {
    return 2.f * __builtin_amdgcn_rcpf(1.f + __expf(-2.f * x)) - 1.f;
}
__device__ __forceinline__ void waitflag(const int* f) {
    while (__hip_atomic_load(f, __ATOMIC_ACQUIRE, __HIP_MEMORY_SCOPE_AGENT) < 32)
        __builtin_amdgcn_s_sleep(1);
}

// ================= mega-kernel with XCD-affine role claiming ================
// Every block reads its physical XCC_ID (m09: works on MI355X). Blocks on
// XCD0 claim dir-0 LSTM slots (32), blocks on XCD1 claim dir-1 (32); everyone
// else takes a gemm tile id from a third counter. Claimers are *running*
// blocks => the 32 WGs of a direction are co-resident AND share one physical
// XCD-L2. The h-exchange then uses sc0 (L1-bypass, L2-scope) loads/stores:
// ~200cy round trip through the shared L2 instead of ~600-900cy through the
// device coherence point. R1's flag handshake (regressed: +2 serial LLC hops)
// is fully reverted to the one-hop data-spin with sentinel.
// Safety: producers dual-store (sc0 local + sc0sc1 LLC copy); consumers
// escalate to agent-scope spin after 20K failed sc0 polls, so a wrong
// XCD-mapping theory degrades to ~baseline speed instead of hanging.
__global__ __launch_bounds__(256, 1) void k_main(
        const int* __restrict__ sent, const float* __restrict__ emb,
        const float* __restrict__ wihf, const float* __restrict__ whhf,
        const float* __restrict__ bfv,
        const float* __restrict__ wihb, const float* __restrict__ whhb,
        const float* __restrict__ bbv,
        const float* __restrict__ h0, const float* __restrict__ c0,
        float* __restrict__ xg, float* __restrict__ hs,
        int* __restrict__ xflag) {
    const int tid = threadIdx.x;

    // ---------------- dynamic role claim (xflag[64],[65]=dir claims, [66]=gemm)
    __shared__ int rs[2];
    if (tid == 0) {
        unsigned xcc;
        asm volatile("s_getreg_b32 %0, hwreg(HW_REG_XCC_ID)" : "=s"(xcc));
        xcc &= 7u;
        int role = 2, idx = 0;
        if (xcc < 2u) {
            int slot = __hip_atomic_fetch_add(&xflag[64 + (int)xcc], 1,
                                              __ATOMIC_RELAXED, __HIP_MEMORY_SCOPE_AGENT);
            if (slot < 32) { role = (int)xcc; idx = slot; }
        }
        if (role == 2)
            idx = __hip_atomic_fetch_add(&xflag[66], 1,
                                         __ATOMIC_RELAXED, __HIP_MEMORY_SCOPE_AGENT);
        rs[0] = role; rs[1] = idx;
    }
    __syncthreads();
    const int role = rs[0];
    const int idx  = rs[1];

    if (role == 2) {
        // ============================ GEMM role ============================
        const int gid  = idx;
        const int gy   = gid >> 5;
        const int jj   = gy >> 1;
        const int dir  = gy & 1;
        const int tile = dir ? (31 - jj) : jj;     // urgent tiles first
        const float* __restrict__ w    = dir ? wihb : wihf;
        const float* __restrict__ bias = dir ? bbv : bfv;
        const int tb = tile * 64;
        const int nb = (gid & 31) * 64;
        __shared__ float As[64][17];
        __shared__ float Bs[64][17];
        const int lr = tid >> 2;
        const int lc = (tid & 3) * 4;
        const int ty = tid >> 4;
        const int tx = tid & 15;
        const int sidx = sent[tb + lr];            // fused embedding gather
        float acc[4][4] = {};
        for (int k0 = 0; k0 < EE; k0 += 16) {
            float4 av = *(const float4*)(emb + (size_t)sidx * EE + k0 + lc);
            float4 bv = *(const float4*)(w + (size_t)(nb + lr) * EE + k0 + lc);
            As[lr][lc+0] = av.x; As[lr][lc+1] = av.y; As[lr][lc+2] = av.z; As[lr][lc+3] = av.w;
            Bs[lr][lc+0] = bv.x; Bs[lr][lc+1] = bv.y; Bs[lr][lc+2] = bv.z; Bs[lr][lc+3] = bv.w;
            __syncthreads();
            #pragma unroll
            for (int kk = 0; kk < 16; ++kk) {
                float a[4], b[4];
                #pragma unroll
                for (int i = 0; i < 4; ++i) a[i] = As[ty*4+i][kk];
                #pragma unroll
                for (int j = 0; j < 4; ++j) b[j] = Bs[tx*4+j][kk];
                #pragma unroll
                for (int i = 0; i < 4; ++i)
                    #pragma unroll
                    for (int j = 0; j < 4; ++j)
                        acc[i][j] += a[i] * b[j];
            }
            __syncthreads();
        }
        #pragma unroll
        for (int i = 0; i < 4; ++i) {
            float4 o;
            o.x = acc[i][0] + bias[nb + tx*4 + 0];
            o.y = acc[i][1] + bias[nb + tx*4 + 1];
            o.z = acc[i][2] + bias[nb + tx*4 + 2];
            o.w = acc[i][3] + bias[nb + tx*4 + 3];
            *(float4*)(xg + ((size_t)dir*TT + tb + ty*4 + i) * 2048 + nb + tx*4) = o;
        }
        __syncthreads();
        if (tid == 0)
            __hip_atomic_fetch_add(&xflag[dir * 32 + tile], 1,
                                   __ATOMIC_RELEASE, __HIP_MEMORY_SCOPE_AGENT);
        return;
    }

    // ============================ LSTM role ================================
    const int dir = role;        // XCD0 -> dir0, XCD1 -> dir1
    const int wg  = idx;         // 0..31 within the direction
    const float* __restrict__ whh = dir ? whhb : whhf;
    const int lane   = tid & 63;
    const int waveid = tid >> 6;
    const int unit   = lane >> 4;        // 0..3
    const int gate   = (lane >> 2) & 3;  // i,f,g,o
    const int seg    = lane & 3;         // k segment (128 floats)
    const int ubase  = (wg * 4 + waveid) * 4;
    const int grow   = gate * HDD + ubase + unit;

    float4 w[32];
    {
        const float4* wp = (const float4*)(whh + (size_t)grow * HDD + seg * 128);
        #pragma unroll
        for (int i = 0; i < 32; ++i) w[i] = wp[i];
    }

    __shared__ float hbuf[2][528];   // double-buffered, padded 4x132

    float c = c0[dir * HDD + ubase + unit];

    const int* flags = xflag + dir * 32;
    const int t0 = dir ? (TT - 1) : 0;
    int curtile = t0 >> 6;
    waitflag(&flags[curtile]);
    float xvn = __uint_as_float(__hip_atomic_load(
        (const unsigned*)(xg + ((size_t)dir * TT + t0) * 2048 + grow),
        __ATOMIC_RELAXED, __HIP_MEMORY_SCOPE_AGENT));

    // stage step 0's h (from h0) into buf 0: 2 consecutive floats per lane
    const int g0 = 2 * tid;
    const int soff = (g0 >> 7) * 132 + (g0 & 127);
    hbuf[0][soff]     = h0[dir * HDD + g0];
    hbuf[0][soff + 1] = h0[dir * HDD + g0 + 1];

    bool slowpath = false;   // sticky escalation if XCD-local theory fails

    for (int s = 0; s < TT; ++s) {
        const int t = dir ? (TT - 1 - s) : s;
        const float xv = xvn;
        if (s + 1 < TT) {
            const int tn = dir ? (TT - 2 - s) : (s + 1);
            const int tilen = tn >> 6;
            if (tilen != curtile) { waitflag(&flags[tilen]); curtile = tilen; }
            xvn = __uint_as_float(__hip_atomic_load(
                (const unsigned*)(xg + ((size_t)dir * TT + tn) * 2048 + grow),
                __ATOMIC_RELAXED, __HIP_MEMORY_SCOPE_AGENT));
        }

        float* hb = hbuf[s & 1];
        if (s > 0) {
            const int tprev = dir ? (t + 1) : (t - 1);
            const unsigned long long* hsrc = (const unsigned long long*)
                (hs + ((size_t)dir * TT + tprev) * HDD) + tid;
            unsigned long long vv = 0;
            bool ok = false;
            if (!slowpath) {
                // fast path: sc0 load = L1-bypass, served by the shared XCD-L2
                int tries = 0;
                do {
                    asm volatile("global_load_dwordx2 %0, %1, off sc0\n\t"
                                 "s_waitcnt vmcnt(0)"
                                 : "=v"(vv) : "v"(hsrc) : "memory");
                    ok = ((unsigned)vv != SENT) && ((unsigned)(vv >> 32) != SENT);
                } while (!ok && ++tries < 20000);
                if (!ok) slowpath = true;
            }
            if (!ok) {
                // fallback: device coherence point (always correct)
                do {
                    vv = __hip_atomic_load(hsrc,
                            __ATOMIC_RELAXED, __HIP_MEMORY_SCOPE_AGENT);
                } while ((unsigned)vv == SENT || (unsigned)(vv >> 32) == SENT);
            }
            hb[soff]     = __uint_as_float((unsigned)vv);
            hb[soff + 1] = __uint_as_float((unsigned)(vv >> 32));
        }
        __syncthreads();

        const float4* hp = (const float4*)(hb + seg * 132);
        float a0 = 0.f, a1 = 0.f, a2 = 0.f, a3 = 0.f;
        #pragma unroll
        for (int i = 0; i < 32; i += 4) {
            float4 h0v = hp[i], h1v = hp[i+1], h2v = hp[i+2], h3v = hp[i+3];
            a0 += w[i  ].x*h0v.x + w[i  ].y*h0v.y + w[i  ].z*h0v.z + w[i  ].w*h0v.w;
            a1 += w[i+1].x*h1v.x + w[i+1].y*h1v.y + w[i+1].z*h1v.z + w[i+1].w*h1v.w;
            a2 += w[i+2].x*h2v.x + w[i+2].y*h2v.y + w[i+2].z*h2v.z + w[i+2].w*h2v.w;
            a3 += w[i+3].x*h3v.x + w[i+3].y*h3v.y + w[i+3].z*h3v.z + w[i+3].w*h3v.w;
        }
        float acc = (a0 + a1) + (a2 + a3);
        acc += __shfl_xor(acc, 1);
        acc += __shfl_xor(acc, 2);
        acc += xv;

        const int base = lane & ~15;
        const float iv = __shfl(acc, base + 0);
        const float fv = __shfl(acc, base + 4);
        const float gv = __shfl(acc, base + 8);
        const float ov = __shfl(acc, base + 12);
        c = fsig(fv) * c + fsig(iv) * ftanh(gv);
        const float h = fsig(ov) * ftanh(c);

        if ((lane & 15) == 0) {
            float* pp = &hs[((size_t)dir * TT + t) * HDD + ubase + unit];
            // fast copy: write-through into the shared XCD-L2 (consumer hits it)
            asm volatile("global_store_dword %0, %1, off sc0"
                         :: "v"(pp), "v"(h) : "memory");
            // safety copy: push to device coherence point for the fallback path
            asm volatile("global_store_dword %0, %1, off sc0 sc1"
                         :: "v"(pp), "v"(h) : "memory");
        }
    }
}

// ------- feats[t][tag] = sum_k concat(hf,hb)[t][k]*W_out[tag][k] + b_out -----
__global__ __launch_bounds__(256) void k_feats(const float* __restrict__ hs,
        const float* __restrict__ Wout, const float* __restrict__ bout,
        float* __restrict__ feats) {
    const int t = blockIdx.x;
    const int tid = threadIdx.x;
    const int tag = tid >> 3;
    const int chunk = tid & 7;
    const float* __restrict__ hrow = (chunk < 4)
        ? hs + (size_t)t * HDD
        : hs + ((size_t)TT + t) * HDD - 512;
    float acc = 0.f;
    const float4* wp = (const float4*)(Wout + (size_t)tag * 1024 + chunk * 128);
    const float4* hp = (const float4*)(hrow + chunk * 128);
    #pragma unroll
    for (int i = 0; i < 32; ++i) {
        float4 wv = wp[i];
        float4 hv = hp[i];
        acc += wv.x*hv.x + wv.y*hv.y + wv.z*hv.z + wv.w*hv.w;
    }
    __shared__ float red[TAGS][9];
    red[tag][chunk] = acc;
    __syncthreads();
    if (tid < TAGS) {
        float s = bout[tid];
        #pragma unroll
        for (int c = 0; c < 8; ++c) s += red[tid][c];
        feats[(size_t)t * TAGS + tid] = s;
    }
}

// ------- Viterbi: single wave; bp in LDS; 2-way prev split per tag ---------
__global__ __launch_bounds__(64) void k_viterbi(const float* __restrict__ feats,
        const float* __restrict__ trans, float* __restrict__ out) {
    const int lane = threadIdx.x;
    const int n  = lane & 31;   // next tag
    const int ph = lane >> 5;   // prev half
    __shared__ float fvs[TAGS];
    __shared__ unsigned char bp[TT][TAGS];            // 64 KiB backtrack
    __shared__ __align__(16) float fbuf[VCH * TAGS];  // 32 KiB feats chunk
    float tr[16];
    #pragma unroll
    for (int p = 0; p < 16; ++p) tr[p] = trans[n * TAGS + ph * 16 + p];
    if (lane < TAGS) fvs[lane] = (lane == STARTT) ? 0.f : NEGV;
    __syncthreads();
    for (int c0 = 0; c0 < TT; c0 += VCH) {
        const float4* src = (const float4*)(feats + (size_t)c0 * TAGS);
        float4* dst = (float4*)fbuf;
        for (int i = lane; i < VCH * TAGS / 4; i += 64) dst[i] = src[i];
        __syncthreads();
        for (int lt = 0; lt < VCH; ++lt) {
            const int t = c0 + lt;
            float bv = fvs[ph * 16] + tr[0];
            int bi = ph * 16;
            #pragma unroll
            for (int p = 1; p < 16; ++p) {
                const float cand = fvs[ph * 16 + p] + tr[p];
                if (cand > bv) { bv = cand; bi = ph * 16 + p; }
            }
            const float obv = __shfl_xor(bv, 32);
            const int   obi = __shfl_xor(bi, 32);
            if (obv > bv || (obv == bv && obi < bi)) { bv = obv; bi = obi; }
            const float nf = bv + fbuf[lt * TAGS + n];
            if (ph == 0) bp[t][n] = (unsigned char)bi;
            __syncthreads();
            if (ph == 0) fvs[n] = nf;
            __syncthreads();
        }
    }
    if (lane < TAGS) fvs[lane] += trans[STOPP * TAGS + lane];
    __syncthreads();
    if (lane == 0) {
        float bs = fvs[0]; int best = 0;
        for (int i = 1; i < TAGS; ++i)
            if (fvs[i] > bs) { bs = fvs[i]; best = i; }
        out[0] = bs;
        int tag = best;
        for (int t = TT - 1; t >= 0; --t) {
            out[1 + t] = (float)tag;
            tag = bp[t][tag];
        }
    }
}

extern "C" void kernel_launch(void* const* d_in, const int* in_sizes, int n_in,
                              void* d_out, int out_size, void* d_ws, size_t ws_size,
                              hipStream_t stream) {
    const int*   sent  = (const int*)  d_in[0];
    const float* emb   = (const float*)d_in[1];
    const float* wihf  = (const float*)d_in[2];
    const float* whhf  = (const float*)d_in[3];
    const float* bfv   = (const float*)d_in[4];
    const float* wihb  = (const float*)d_in[5];
    const float* whhb  = (const float*)d_in[6];
    const float* bbv   = (const float*)d_in[7];
    const float* Wout  = (const float*)d_in[8];
    const float* bout  = (const float*)d_in[9];
    const float* trans = (const float*)d_in[10];
    const float* h0    = (const float*)d_in[11];
    const float* c0    = (const float*)d_in[12];
    float* out = (float*)d_out;

    char* ws = (char*)d_ws;
    float* xg    = (float*)(ws + ((size_t)4  << 20));             // 32 MiB [2][T][2048]
    float* hs    = (float*)(ws + ((size_t)36 << 20));             //  8 MiB [2][T][512]
    float* feats = (float*)(ws + ((size_t)44 << 20));             // 256 KiB
    int* xflag   = (int*)  (ws + ((size_t)44 << 20) + (320u << 10)); // flags + claims

    hipMemsetAsync(hs, 0xFF, (size_t)2 * TT * HDD * sizeof(float), stream);
    hipMemsetAsync(xflag, 0, 128 * sizeof(int), stream);
    k_main   <<<dim3(64 + 2048), 256, 0, stream>>>(sent, emb, wihf, whhf, bfv,
                                                   wihb, whhb, bbv, h0, c0,
                                                   xg, hs, xflag);
    k_feats  <<<TT, 256, 0, stream>>>(hs, Wout, bout, feats);
    k_viterbi<<<1, 64, 0, stream>>>(feats, trans, out);
}

// Round 3
// 4154.482 us; speedup vs baseline: 12.3330x; 12.3330x over previous
//
#include <hip/hip_runtime.h>
#include <math.h>

#define TT 2048
#define EE 512
#define HDD 512
#define TAGS 32
#define STARTT 30
#define STOPP 31
#define NEGV -10000.0f
#define VCH 256
#define SENT 0xFFFFFFFFu   // hs sentinel: -NaN bit pattern, unreachable for finite h

__device__ __forceinline__ float fsig(float x) {
    return __builtin_amdgcn_rcpf(1.f + __expf(-x));
}
__device__ __forceinline__ float ftanh(float x) {
    return 2.f * __builtin_amdgcn_rcpf(1.f + __expf(-2.f * x)) - 1.f;
}
__device__ __forceinline__ void waitflag(const int* f) {
    while (__hip_atomic_load(f, __ATOMIC_ACQUIRE, __HIP_MEMORY_SCOPE_AGENT) < 32)
        __builtin_amdgcn_s_sleep(1);
}

// ================= mega-kernel: gemm-role + lstm-role, truly concurrent =====
// blocks 0..127  : LSTM WGs (wg = bid&63, dir = bid>>6). Dispatched first ->
//                  co-resident before gemm blocks (capacity 512 blocks).
// blocks 128..2175: xgemm tiles, urgent-first ordering; release-add xflag
//                  after tile store.
// h-exchange: the PROVEN one-hop agent-scope data-spin with sentinel (R0,
// 4446us). R1 (wave flags: +2 LLC hops) and R2 (sc0 L2 spin: visibility
// depended on line eviction -> 51ms) are both reverted.
// This round's single change: K-split re-partition. 64 WGs/dir; each dot
// product uses 8 lanes x 64 floats (was 4 x 128) -> per-lane serial tail
// halves (16 ds_read_b128 + 64 FMAs), cutting the latency-critical path.
__global__ __launch_bounds__(256, 2) void k_main(
        const int* __restrict__ sent, const float* __restrict__ emb,
        const float* __restrict__ wihf, const float* __restrict__ whhf,
        const float* __restrict__ bfv,
        const float* __restrict__ wihb, const float* __restrict__ whhb,
        const float* __restrict__ bbv,
        const float* __restrict__ h0, const float* __restrict__ c0,
        float* __restrict__ xg, float* __restrict__ hs,
        int* __restrict__ xflag) {
    const int tid = threadIdx.x;

    if (blockIdx.x >= 128) {
        // ============================ GEMM role ============================
        const int gid  = blockIdx.x - 128;
        const int gy   = gid >> 5;
        const int jj   = gy >> 1;
        const int dir  = gy & 1;
        const int tile = dir ? (31 - jj) : jj;     // urgent tiles first
        const float* __restrict__ w    = dir ? wihb : wihf;
        const float* __restrict__ bias = dir ? bbv : bfv;
        const int tb = tile * 64;
        const int nb = (gid & 31) * 64;
        __shared__ float As[64][17];
        __shared__ float Bs[64][17];
        const int lr = tid >> 2;
        const int lc = (tid & 3) * 4;
        const int ty = tid >> 4;
        const int tx = tid & 15;
        const int sidx = sent[tb + lr];            // fused embedding gather
        float acc[4][4] = {};
        for (int k0 = 0; k0 < EE; k0 += 16) {
            float4 av = *(const float4*)(emb + (size_t)sidx * EE + k0 + lc);
            float4 bv = *(const float4*)(w + (size_t)(nb + lr) * EE + k0 + lc);
            As[lr][lc+0] = av.x; As[lr][lc+1] = av.y; As[lr][lc+2] = av.z; As[lr][lc+3] = av.w;
            Bs[lr][lc+0] = bv.x; Bs[lr][lc+1] = bv.y; Bs[lr][lc+2] = bv.z; Bs[lr][lc+3] = bv.w;
            __syncthreads();
            #pragma unroll
            for (int kk = 0; kk < 16; ++kk) {
                float a[4], b[4];
                #pragma unroll
                for (int i = 0; i < 4; ++i) a[i] = As[ty*4+i][kk];
                #pragma unroll
                for (int j = 0; j < 4; ++j) b[j] = Bs[tx*4+j][kk];
                #pragma unroll
                for (int i = 0; i < 4; ++i)
                    #pragma unroll
                    for (int j = 0; j < 4; ++j)
                        acc[i][j] += a[i] * b[j];
            }
            __syncthreads();
        }
        #pragma unroll
        for (int i = 0; i < 4; ++i) {
            float4 o;
            o.x = acc[i][0] + bias[nb + tx*4 + 0];
            o.y = acc[i][1] + bias[nb + tx*4 + 1];
            o.z = acc[i][2] + bias[nb + tx*4 + 2];
            o.w = acc[i][3] + bias[nb + tx*4 + 3];
            *(float4*)(xg + ((size_t)dir*TT + tb + ty*4 + i) * 2048 + nb + tx*4) = o;
        }
        __syncthreads();
        if (tid == 0)
            __hip_atomic_fetch_add(&xflag[dir * 32 + tile], 1,
                                   __ATOMIC_RELEASE, __HIP_MEMORY_SCOPE_AGENT);
        return;
    }

    // ============================ LSTM role ================================
    const int wg  = blockIdx.x & 63;     // 0..63 within direction
    const int dir = blockIdx.x >> 6;     // 0..1
    const float* __restrict__ whh = dir ? whhb : whhf;
    const int lane   = tid & 63;
    const int waveid = tid >> 6;
    const int unit   = lane >> 5;        // 0..1
    const int gate   = (lane >> 3) & 3;  // i,f,g,o
    const int seg    = lane & 7;         // k segment (64 floats)
    const int hidx   = (wg * 4 + waveid) * 2 + unit;   // 0..511
    const int grow   = gate * HDD + hidx;

    float4 w[16];
    {
        const float4* wp = (const float4*)(whh + (size_t)grow * HDD + seg * 64);
        #pragma unroll
        for (int i = 0; i < 16; ++i) w[i] = wp[i];
    }

    __shared__ float hbuf[2][528];   // double-buffered, padded 4x132

    float c = c0[dir * HDD + hidx];

    const int* flags = xflag + dir * 32;
    const int t0 = dir ? (TT - 1) : 0;
    int curtile = t0 >> 6;
    waitflag(&flags[curtile]);
    float xvn = __uint_as_float(__hip_atomic_load(
        (const unsigned*)(xg + ((size_t)dir * TT + t0) * 2048 + grow),
        __ATOMIC_RELAXED, __HIP_MEMORY_SCOPE_AGENT));

    // stage step 0's h (from h0) into buf 0: 2 consecutive floats per lane
    const int g0 = 2 * tid;
    const int soff = (g0 >> 7) * 132 + (g0 & 127);
    hbuf[0][soff]     = h0[dir * HDD + g0];
    hbuf[0][soff + 1] = h0[dir * HDD + g0 + 1];

    for (int s = 0; s < TT; ++s) {
        const int t = dir ? (TT - 1 - s) : s;
        const float xv = xvn;
        if (s + 1 < TT) {
            const int tn = dir ? (TT - 2 - s) : (s + 1);
            const int tilen = tn >> 6;
            if (tilen != curtile) { waitflag(&flags[tilen]); curtile = tilen; }
            xvn = __uint_as_float(__hip_atomic_load(
                (const unsigned*)(xg + ((size_t)dir * TT + tn) * 2048 + grow),
                __ATOMIC_RELAXED, __HIP_MEMORY_SCOPE_AGENT));
        }

        float* hb = hbuf[s & 1];
        if (s > 0) {
            const int tprev = dir ? (t + 1) : (t - 1);
            const unsigned long long* hsrc = (const unsigned long long*)
                (hs + ((size_t)dir * TT + tprev) * HDD) + tid;
            unsigned long long vv = __hip_atomic_load(hsrc,
                    __ATOMIC_RELAXED, __HIP_MEMORY_SCOPE_AGENT);
            while ((unsigned)vv == SENT || (unsigned)(vv >> 32) == SENT)
                vv = __hip_atomic_load(hsrc,
                        __ATOMIC_RELAXED, __HIP_MEMORY_SCOPE_AGENT);
            hb[soff]     = __uint_as_float((unsigned)vv);
            hb[soff + 1] = __uint_as_float((unsigned)(vv >> 32));
        }
        __syncthreads();

        // dot over this lane's 64-float segment of h
        const float4* hp = (const float4*)(hb + (seg >> 1) * 132 + (seg & 1) * 64);
        float a0 = 0.f, a1 = 0.f, a2 = 0.f, a3 = 0.f;
        #pragma unroll
        for (int i = 0; i < 16; i += 4) {
            float4 h0v = hp[i], h1v = hp[i+1], h2v = hp[i+2], h3v = hp[i+3];
            a0 += w[i  ].x*h0v.x + w[i  ].y*h0v.y + w[i  ].z*h0v.z + w[i  ].w*h0v.w;
            a1 += w[i+1].x*h1v.x + w[i+1].y*h1v.y + w[i+1].z*h1v.z + w[i+1].w*h1v.w;
            a2 += w[i+2].x*h2v.x + w[i+2].y*h2v.y + w[i+2].z*h2v.z + w[i+2].w*h2v.w;
            a3 += w[i+3].x*h3v.x + w[i+3].y*h3v.y + w[i+3].z*h3v.z + w[i+3].w*h3v.w;
        }
        float acc = (a0 + a1) + (a2 + a3);
        acc += __shfl_xor(acc, 1);
        acc += __shfl_xor(acc, 2);
        acc += __shfl_xor(acc, 4);
        acc += xv;

        const int base = lane & ~31;     // unit-group base (0 or 32)
        const float iv = __shfl(acc, base + 0);
        const float fv = __shfl(acc, base + 8);
        const float gv = __shfl(acc, base + 16);
        const float ov = __shfl(acc, base + 24);
        c = fsig(fv) * c + fsig(iv) * ftanh(gv);
        const float h = fsig(ov) * ftanh(c);

        if ((lane & 31) == 0)
            __hip_atomic_store(&hs[((size_t)dir * TT + t) * HDD + hidx], h,
                               __ATOMIC_RELAXED, __HIP_MEMORY_SCOPE_AGENT);
    }
}

// ------- feats[t][tag] = sum_k concat(hf,hb)[t][k]*W_out[tag][k] + b_out -----
__global__ __launch_bounds__(256) void k_feats(const float* __restrict__ hs,
        const float* __restrict__ Wout, const float* __restrict__ bout,
        float* __restrict__ feats) {
    const int t = blockIdx.x;
    const int tid = threadIdx.x;
    const int tag = tid >> 3;
    const int chunk = tid & 7;
    const float* __restrict__ hrow = (chunk < 4)
        ? hs + (size_t)t * HDD
        : hs + ((size_t)TT + t) * HDD - 512;
    float acc = 0.f;
    const float4* wp = (const float4*)(Wout + (size_t)tag * 1024 + chunk * 128);
    const float4* hp = (const float4*)(hrow + chunk * 128);
    #pragma unroll
    for (int i = 0; i < 32; ++i) {
        float4 wv = wp[i];
        float4 hv = hp[i];
        acc += wv.x*hv.x + wv.y*hv.y + wv.z*hv.z + wv.w*hv.w;
    }
    __shared__ float red[TAGS][9];
    red[tag][chunk] = acc;
    __syncthreads();
    if (tid < TAGS) {
        float s = bout[tid];
        #pragma unroll
        for (int c = 0; c < 8; ++c) s += red[tid][c];
        feats[(size_t)t * TAGS + tid] = s;
    }
}

// ------- Viterbi: single wave; bp in LDS; 2-way prev split per tag ---------
__global__ __launch_bounds__(64) void k_viterbi(const float* __restrict__ feats,
        const float* __restrict__ trans, float* __restrict__ out) {
    const int lane = threadIdx.x;
    const int n  = lane & 31;   // next tag
    const int ph = lane >> 5;   // prev half
    __shared__ float fvs[TAGS];
    __shared__ unsigned char bp[TT][TAGS];            // 64 KiB backtrack
    __shared__ __align__(16) float fbuf[VCH * TAGS];  // 32 KiB feats chunk
    float tr[16];
    #pragma unroll
    for (int p = 0; p < 16; ++p) tr[p] = trans[n * TAGS + ph * 16 + p];
    if (lane < TAGS) fvs[lane] = (lane == STARTT) ? 0.f : NEGV;
    __syncthreads();
    for (int c0 = 0; c0 < TT; c0 += VCH) {
        const float4* src = (const float4*)(feats + (size_t)c0 * TAGS);
        float4* dst = (float4*)fbuf;
        for (int i = lane; i < VCH * TAGS / 4; i += 64) dst[i] = src[i];
        __syncthreads();
        for (int lt = 0; lt < VCH; ++lt) {
            const int t = c0 + lt;
            float bv = fvs[ph * 16] + tr[0];
            int bi = ph * 16;
            #pragma unroll
            for (int p = 1; p < 16; ++p) {
                const float cand = fvs[ph * 16 + p] + tr[p];
                if (cand > bv) { bv = cand; bi = ph * 16 + p; }
            }
            const float obv = __shfl_xor(bv, 32);
            const int   obi = __shfl_xor(bi, 32);
            if (obv > bv || (obv == bv && obi < bi)) { bv = obv; bi = obi; }
            const float nf = bv + fbuf[lt * TAGS + n];
            if (ph == 0) bp[t][n] = (unsigned char)bi;
            __syncthreads();
            if (ph == 0) fvs[n] = nf;
            __syncthreads();
        }
    }
    if (lane < TAGS) fvs[lane] += trans[STOPP * TAGS + lane];
    __syncthreads();
    if (lane == 0) {
        float bs = fvs[0]; int best = 0;
        for (int i = 1; i < TAGS; ++i)
            if (fvs[i] > bs) { bs = fvs[i]; best = i; }
        out[0] = bs;
        int tag = best;
        for (int t = TT - 1; t >= 0; --t) {
            out[1 + t] = (float)tag;
            tag = bp[t][tag];
        }
    }
}

extern "C" void kernel_launch(void* const* d_in, const int* in_sizes, int n_in,
                              void* d_out, int out_size, void* d_ws, size_t ws_size,
                              hipStream_t stream) {
    const int*   sent  = (const int*)  d_in[0];
    const float* emb   = (const float*)d_in[1];
    const float* wihf  = (const float*)d_in[2];
    const float* whhf  = (const float*)d_in[3];
    const float* bfv   = (const float*)d_in[4];
    const float* wihb  = (const float*)d_in[5];
    const float* whhb  = (const float*)d_in[6];
    const float* bbv   = (const float*)d_in[7];
    const float* Wout  = (const float*)d_in[8];
    const float* bout  = (const float*)d_in[9];
    const float* trans = (const float*)d_in[10];
    const float* h0    = (const float*)d_in[11];
    const float* c0    = (const float*)d_in[12];
    float* out = (float*)d_out;

    char* ws = (char*)d_ws;
    float* xg    = (float*)(ws + ((size_t)4  << 20));             // 32 MiB [2][T][2048]
    float* hs    = (float*)(ws + ((size_t)36 << 20));             //  8 MiB [2][T][512]
    float* feats = (float*)(ws + ((size_t)44 << 20));             // 256 KiB
    int* xflag   = (int*)  (ws + ((size_t)44 << 20) + (320u << 10)); // 64 ints

    hipMemsetAsync(hs, 0xFF, (size_t)2 * TT * HDD * sizeof(float), stream);
    hipMemsetAsync(xflag, 0, 64 * sizeof(int), stream);
    k_main   <<<dim3(128 + 2048), 256, 0, stream>>>(sent, emb, wihf, whhf, bfv,
                                                    wihb, whhb, bbv, h0, c0,
                                                    xg, hs, xflag);
    k_feats  <<<TT, 256, 0, stream>>>(hs, Wout, bout, feats);
    k_viterbi<<<1, 64, 0, stream>>>(feats, trans, out);
}